// Round 2
// baseline (1544.728 us; speedup 1.0000x reference)
//
#include <hip/hip_runtime.h>
#include <math.h>

#define N_TOK   16384
#define EDIM    64
#define NE      4096
#define NSLICE  16                       /* 16 slices x 256 codes */
#define TPB     256
#define ZQ_OFF  1
#define IDX_OFF (1 + N_TOK * EDIM)       /* 1048577 */
#define PERP_OFF (IDX_OFF + N_TOK)       /* 1064961 */

typedef unsigned long long u64;

// ---------------------------------------------------------------------------
// Kernel A: per-row squared norms replicating numpy pairwise_sum (n=64 path:
// 8 accumulators stride 8, then ((r0+r1)+(r2+r3))+((r4+r5)+(r6+r7))),
// with products ROUNDED before summation (contract off). Also zero-inits
// the histogram and loss accumulator, and NOW also writes the transposed
// codebook cbT[dim][code] (1 MB) so kernel B can stream codes through the
// SCALAR pipe (wave-uniform operand). Stores for fixed dim are coalesced
// across consecutive code-threads.
// ---------------------------------------------------------------------------
__global__ __launch_bounds__(256) void norms_zero_kernel(
    const float* __restrict__ z, const float* __restrict__ cb,
    float* __restrict__ nz, float* __restrict__ ne,
    int* __restrict__ hist, float* __restrict__ lossAcc,
    float* __restrict__ cbT) {
#pragma clang fp contract(off)
    int i = blockIdx.x * 256 + threadIdx.x;
    if (i < NE) hist[i] = 0;
    if (i == 0) lossAcc[0] = 0.0f;
    const float* row;
    float* dst;
    int ci = -1;
    if (i < N_TOK)            { row = z  + (size_t)i * EDIM;           dst = nz + i; }
    else if (i < N_TOK + NE)  { ci = i - N_TOK;
                                row = cb + (size_t)ci * EDIM;          dst = ne + ci; }
    else return;

    float r[8];
#pragma unroll
    for (int j = 0; j < 8; ++j) {
        float v = row[j];
        r[j] = v * v;
        if (ci >= 0) cbT[(size_t)j * NE + ci] = v;
    }
#pragma unroll
    for (int b = 8; b < 64; b += 8) {
#pragma unroll
        for (int j = 0; j < 8; ++j) {
            float v = row[b + j];
            r[j] = r[j] + v * v;
            if (ci >= 0) cbT[(size_t)(b + j) * NE + ci] = v;
        }
    }
    dst[0] = ((r[0] + r[1]) + (r[2] + r[3])) + ((r[4] + r[5]) + (r[6] + r[7]));
}

// ---------------------------------------------------------------------------
// Kernel B (v3): scalar-pipe code streaming, zero LDS.
// Previous version was LDS-pipe-bound: 16384 ds_read_b128/CU x ~12cyc = 82us
// on the single per-CU LDS pipe vs a 55us VALU floor. Codes are WAVE-UNIFORM
// (lanes = tokens), so they belong on the scalar pipe: read cbT rows
// (dim-major, 8 contiguous codes) via uniform loads -> s_load_dwordx8.
// Each thread keeps its 2 tokens entirely in VGPRs (128 regs); the FMA is
// v_fma_f32 vacc, vz, s_code (one SGPR operand -> legal). Main loop issues
// NO LDS and NO per-lane VMEM traffic.
// Numerics: per-(token,code) dot is the SAME sequential q-ascending,
// x->w-ascending fp32 FMA chain as the passing kernels (bits identical ->
// ties exact). d = fma(-2, dot, nz+ne[k]); argmin packed (d_bits<<32)|k,
// u64 min == first-index tie-break (d>0 so float bits monotone).
// ---------------------------------------------------------------------------
__global__ __launch_bounds__(256, 2) void dist_argmin_kernel(
    const float* __restrict__ z, const float* __restrict__ cbT,
    const float* __restrict__ nz, const float* __restrict__ ne,
    u64* __restrict__ part) {
    const int tid    = threadIdx.x;
    const int token0 = blockIdx.x * 512 + tid;      // tokens tid, tid+256
    const int token1 = token0 + 256;
    const int slice  = blockIdx.y;

    float zr0[EDIM], zr1[EDIM];
    {
        const float4* zp0 = (const float4*)(z + (size_t)token0 * EDIM);
        const float4* zp1 = (const float4*)(z + (size_t)token1 * EDIM);
#pragma unroll
        for (int j = 0; j < 16; ++j) {
            float4 v = zp0[j];
            zr0[4 * j + 0] = v.x; zr0[4 * j + 1] = v.y;
            zr0[4 * j + 2] = v.z; zr0[4 * j + 3] = v.w;
            float4 w = zp1[j];
            zr1[4 * j + 0] = w.x; zr1[4 * j + 1] = w.y;
            zr1[4 * j + 2] = w.z; zr1[4 * j + 3] = w.w;
        }
    }
    const float tnz0 = nz[token0];
    const float tnz1 = nz[token1];
    u64 best0 = ~0ull, best1 = ~0ull;
    const int kb0 = slice * 256;

#pragma unroll 1
    for (int ch = 0; ch < 32; ++ch) {               // 8 codes per chunk
        const int kb = kb0 + ch * 8;
        float a0[8], a1[8];
#pragma unroll
        for (int j = 0; j < 8; ++j) { a0[j] = 0.0f; a1[j] = 0.0f; }

#pragma unroll
        for (int q = 0; q < 16; ++q) {
            // rows of cbT: dims 4q..4q+3, codes kb..kb+7 (uniform -> s_load)
            const float* c0 = cbT + (size_t)(4 * q + 0) * NE + kb;
            const float* c1 = cbT + (size_t)(4 * q + 1) * NE + kb;
            const float* c2 = cbT + (size_t)(4 * q + 2) * NE + kb;
            const float* c3 = cbT + (size_t)(4 * q + 3) * NE + kb;
#pragma unroll
            for (int j = 0; j < 8; ++j) {
                const float w0 = c0[j], w1 = c1[j], w2 = c2[j], w3 = c3[j];
                a0[j] = __builtin_fmaf(zr0[4 * q + 0], w0, a0[j]);
                a0[j] = __builtin_fmaf(zr0[4 * q + 1], w1, a0[j]);
                a0[j] = __builtin_fmaf(zr0[4 * q + 2], w2, a0[j]);
                a0[j] = __builtin_fmaf(zr0[4 * q + 3], w3, a0[j]);
                a1[j] = __builtin_fmaf(zr1[4 * q + 0], w0, a1[j]);
                a1[j] = __builtin_fmaf(zr1[4 * q + 1], w1, a1[j]);
                a1[j] = __builtin_fmaf(zr1[4 * q + 2], w2, a1[j]);
                a1[j] = __builtin_fmaf(zr1[4 * q + 3], w3, a1[j]);
            }
        }

#pragma unroll
        for (int j = 0; j < 8; ++j) {
            const float s  = ne[kb + j];            // uniform -> s_load
            const float d0 = __builtin_fmaf(-2.0f, a0[j], tnz0 + s);
            const float d1 = __builtin_fmaf(-2.0f, a1[j], tnz1 + s);
            u64 p;
            p = ((u64)__float_as_uint(d0) << 32) | (u64)(kb + j); if (p < best0) best0 = p;
            p = ((u64)__float_as_uint(d1) << 32) | (u64)(kb + j); if (p < best1) best1 = p;
        }
    }
    part[(size_t)slice * N_TOK + token0] = best0;
    part[(size_t)slice * N_TOK + token1] = best1;
}

// ---------------------------------------------------------------------------
// Kernel C: combine 16 slice-partials (u64 min keeps first-index tie-break),
// write idx as float, histogram, gather z_q, write z_q_st = z + (z_q - z)
// exactly as the reference computes it, and accumulate sum((z_q - z)^2).
// (unchanged)
// ---------------------------------------------------------------------------
__global__ __launch_bounds__(256) void reduce_gather_kernel(
    const float* __restrict__ z, const float* __restrict__ cb,
    const u64* __restrict__ part, int* __restrict__ hist,
    float* __restrict__ lossAcc, float* __restrict__ out) {
    const int t = blockIdx.x * 256 + threadIdx.x;
    u64 best = part[t];
#pragma unroll
    for (int s = 1; s < NSLICE; ++s) {
        u64 p = part[(size_t)s * N_TOK + t];
        if (p < best) best = p;
    }
    const int idx = (int)(best & 0xFFFFFFFFull);
    out[IDX_OFF + t] = (float)idx;
    atomicAdd(&hist[idx], 1);

    const float4* ev = (const float4*)(cb + (size_t)idx * EDIM);
    const float4* zv = (const float4*)(z + (size_t)t * EDIM);
    float* o = out + ZQ_OFF + (size_t)t * EDIM;  // out+1: only 4B-aligned -> scalar stores
    float acc = 0.0f;
#pragma unroll
    for (int j = 0; j < 16; ++j) {
        float4 e = ev[j], zz = zv[j];
        float d;
        d = e.x - zz.x; o[4 * j + 0] = zz.x + d; acc = __builtin_fmaf(d, d, acc);
        d = e.y - zz.y; o[4 * j + 1] = zz.y + d; acc = __builtin_fmaf(d, d, acc);
        d = e.z - zz.z; o[4 * j + 2] = zz.z + d; acc = __builtin_fmaf(d, d, acc);
        d = e.w - zz.w; o[4 * j + 3] = zz.w + d; acc = __builtin_fmaf(d, d, acc);
    }
    __shared__ float red[256];
    red[threadIdx.x] = acc;
    __syncthreads();
    for (int s = 128; s > 0; s >>= 1) {
        if (threadIdx.x < s) red[threadIdx.x] += red[threadIdx.x + s];
        __syncthreads();
    }
    if (threadIdx.x == 0) atomicAdd(lossAcc, red[0]);
}

// ---------------------------------------------------------------------------
// Kernel D: perplexity from histogram + loss finalize. (unchanged)
// ---------------------------------------------------------------------------
__global__ __launch_bounds__(256) void finalize_kernel(
    const int* __restrict__ hist, const float* __restrict__ lossAcc,
    float* __restrict__ out) {
    __shared__ float red[256];
    float acc = 0.0f;
    for (int i = threadIdx.x; i < NE; i += 256) {
        float e = (float)hist[i] * (1.0f / 16384.0f);  // exact /n_tokens
        acc += e * logf(e + 1e-10f);
    }
    red[threadIdx.x] = acc;
    __syncthreads();
    for (int s = 128; s > 0; s >>= 1) {
        if (threadIdx.x < s) red[threadIdx.x] += red[threadIdx.x + s];
        __syncthreads();
    }
    if (threadIdx.x == 0) {
        out[PERP_OFF] = expf(-red[0]);
        float m = lossAcc[0] * (1.0f / 1048576.0f);    // exact /B*T*E
        out[0] = m + 0.25f * m;
    }
}

extern "C" void kernel_launch(void* const* d_in, const int* in_sizes, int n_in,
                              void* d_out, int out_size, void* d_ws, size_t ws_size,
                              hipStream_t stream) {
    const float* z  = (const float*)d_in[0];
    const float* cb = (const float*)d_in[1];
    float* out = (float*)d_out;

    char* ws = (char*)d_ws;
    u64*   part    = (u64*)ws;                                  // 2 MB
    float* nz      = (float*)(ws + (size_t)NSLICE * N_TOK * 8); // 64 KB
    float* ne      = nz + N_TOK;                                // 16 KB
    int*   hist    = (int*)(ne + NE);                           // 16 KB
    float* lossAcc = (float*)(hist + NE);                       // 4 B (+pad)
    float* cbT     = (float*)(ws + 2195712);                    // 1 MB, 256B-aligned

    hipLaunchKernelGGL(norms_zero_kernel, dim3(80), dim3(256), 0, stream,
                       z, cb, nz, ne, hist, lossAcc, cbT);
    hipLaunchKernelGGL(dist_argmin_kernel,
                       dim3(N_TOK / 512, NSLICE), dim3(TPB), 0, stream,
                       z, cbT, nz, ne, part);
    hipLaunchKernelGGL(reduce_gather_kernel, dim3(64), dim3(256), 0, stream,
                       z, cb, part, hist, lossAcc, out);
    hipLaunchKernelGGL(finalize_kernel, dim3(1), dim3(256), 0, stream,
                       hist, lossAcc, out);
}

// Round 3
// 294.961 us; speedup vs baseline: 5.2371x; 5.2371x over previous
//
#include <hip/hip_runtime.h>
#include <math.h>

#define N_TOK   16384
#define EDIM    64
#define NE      4096
#define NSLICE  16                       /* 16 slices x 256 codes */
#define TPB     256
#define ZQ_OFF  1
#define IDX_OFF (1 + N_TOK * EDIM)       /* 1048577 */
#define PERP_OFF (IDX_OFF + N_TOK)       /* 1064961 */

typedef unsigned long long u64;

// ---------------------------------------------------------------------------
// Kernel A: per-row squared norms replicating numpy pairwise_sum (n=64 path:
// 8 accumulators stride 8, then ((r0+r1)+(r2+r3))+((r4+r5)+(r6+r7))),
// with products ROUNDED before summation (contract off). Also zero-inits
// the histogram and loss accumulator in ws. (round-1 version, cbT removed)
// ---------------------------------------------------------------------------
__global__ __launch_bounds__(256) void norms_zero_kernel(
    const float* __restrict__ z, const float* __restrict__ cb,
    float* __restrict__ nz, float* __restrict__ ne,
    int* __restrict__ hist, float* __restrict__ lossAcc) {
#pragma clang fp contract(off)
    int i = blockIdx.x * 256 + threadIdx.x;
    if (i < NE) hist[i] = 0;
    if (i == 0) lossAcc[0] = 0.0f;
    const float* row;
    float* dst;
    if (i < N_TOK)            { row = z  + (size_t)i * EDIM;           dst = nz + i; }
    else if (i < N_TOK + NE)  { row = cb + (size_t)(i - N_TOK) * EDIM; dst = ne + (i - N_TOK); }
    else return;

    float r[8];
#pragma unroll
    for (int j = 0; j < 8; ++j) { float v = row[j]; r[j] = v * v; }
#pragma unroll
    for (int b = 8; b < 64; b += 8) {
#pragma unroll
        for (int j = 0; j < 8; ++j) { float v = row[b + j]; r[j] = r[j] + v * v; }
    }
    dst[0] = ((r[0] + r[1]) + (r[2] + r[3])) + ((r[4] + r[5]) + (r[6] + r[7]));
}

// ---------------------------------------------------------------------------
// Kernel B (v4): 16x16 register tile, 256x256 block tile, 1 block/CU.
// LDS law: FMA:ds_read_b128 = 4tc/(t+c); balance vs pipes (4 SIMD x 0.5
// instr/cy VALU vs 1 LDS pipe x ~12cy/b128) needs >=24. Round-1's 8x8 tile
// = 16 -> LDS-bound (82us pipe vs 55us VALU floor). 16x16 -> 32: VALU-bound.
// acc 256 + cf 64 + zf ~8 VGPRs -> launch_bounds(256,1), 512-reg budget,
// no spill. LDS 128 KB: zt/ct as float4 [q][row^q] -> tg-reads = 16
// consecutive float4 (2-way = free), cg-reads broadcast, staging writes
// spread over all 8 bank-quads. q-loop kept ROLLED so body fits I$.
// Numerics: per-(token,code) dot is the SAME sequential q-ascending,
// x->w-ascending fp32 FMA chain as the passing kernels (bits identical ->
// ties exact). d = fma(-2, dot, nz+ne[k]); in-thread argmin strict-less
// (j ascending -> first-index), then u64 pack (d_bits<<32)|k, u64 min
// across threads == first-index tie-break (d>0 so float bits monotone).
// ---------------------------------------------------------------------------
__global__ __launch_bounds__(256, 1) void dist_argmin_kernel(
    const float* __restrict__ z, const float* __restrict__ cb,
    const float* __restrict__ nz, const float* __restrict__ ne,
    u64* __restrict__ part) {
    __shared__ float4 zt[4096];          // 64 KB: [q][token^q], 256 tokens
    __shared__ float4 ct[4096];          // 64 KB: [q][code^q],  256 codes
    const int tid   = threadIdx.x;
    const int tg    = tid & 15;          // token group
    const int cg    = tid >> 4;          // code group
    const int tok0  = blockIdx.x * 256;
    const int kbase = blockIdx.y * 256;  // slice

    // ---- stage both tiles; global reads perfectly coalesced (f contiguous)
    {
        const float4* zp = (const float4*)z  + (size_t)tok0  * 16;
        const float4* cp = (const float4*)cb + (size_t)kbase * 16;
#pragma unroll
        for (int r = 0; r < 16; ++r) {
            const int f   = r * 256 + tid;   // = row*16 + q
            const int row = f >> 4;
            const int q   = f & 15;
            zt[q * 256 + (row ^ q)] = zp[f];
            ct[q * 256 + (row ^ q)] = cp[f];
        }
    }
    __syncthreads();

    float acc[16][16];
#pragma unroll
    for (int i = 0; i < 16; ++i)
#pragma unroll
        for (int j = 0; j < 16; ++j) acc[i][j] = 0.0f;

#pragma unroll 1
    for (int q = 0; q < 16; ++q) {       // rolled: body ~1k instrs, fits I$
        const float4* zq = zt + q * 256;
        const float4* cq = ct + q * 256;
        const int tgq = tg ^ q;
        const int cgq = cg ^ q;
        float4 cf[16];
#pragma unroll
        for (int j = 0; j < 16; ++j) cf[j] = cq[16 * j + cgq];
#pragma unroll
        for (int i = 0; i < 16; ++i) {
            const float4 zf = zq[16 * i + tgq];
#pragma unroll
            for (int j = 0; j < 16; ++j) {
                acc[i][j] = __builtin_fmaf(zf.x, cf[j].x, acc[i][j]);
                acc[i][j] = __builtin_fmaf(zf.y, cf[j].y, acc[i][j]);
                acc[i][j] = __builtin_fmaf(zf.z, cf[j].z, acc[i][j]);
                acc[i][j] = __builtin_fmaf(zf.w, cf[j].w, acc[i][j]);
            }
        }
    }

    // ---- epilogue: d + per-thread argmin (strict < keeps lowest k)
    float tnz[16];
#pragma unroll
    for (int i = 0; i < 16; ++i) tnz[i] = nz[tok0 + 16 * i + tg];
    float sne[16];
#pragma unroll
    for (int j = 0; j < 16; ++j) sne[j] = ne[kbase + 16 * j + cg];

    u64 pb[16];
#pragma unroll
    for (int i = 0; i < 16; ++i) {
        float bd = __builtin_fmaf(-2.0f, acc[i][0], tnz[i] + sne[0]);
        int   bk = kbase + cg;
#pragma unroll
        for (int j = 1; j < 16; ++j) {
            const float d = __builtin_fmaf(-2.0f, acc[i][j], tnz[i] + sne[j]);
            const int   k = kbase + 16 * j + cg;
            if (d < bd) { bd = d; bk = k; }
        }
        pb[i] = ((u64)__float_as_uint(bd) << 32) | (u64)bk;
    }

    // ---- cross-thread (cg) reduction in LDS overlay on ct
    __syncthreads();
    u64* red = (u64*)ct;                 // 16 cg x 256 tokens = 32 KB
#pragma unroll
    for (int i = 0; i < 16; ++i) red[cg * 256 + 16 * i + tg] = pb[i];
    __syncthreads();
    u64 b = red[tid];
#pragma unroll
    for (int s = 1; s < 16; ++s) {
        const u64 p = red[s * 256 + tid];
        if (p < b) b = p;
    }
    part[(size_t)blockIdx.y * N_TOK + tok0 + tid] = b;
}

// ---------------------------------------------------------------------------
// Kernel C: combine 16 slice-partials (u64 min keeps first-index tie-break),
// write idx as float, histogram, gather z_q, write z_q_st = z + (z_q - z)
// exactly as the reference computes it, and accumulate sum((z_q - z)^2).
// (unchanged)
// ---------------------------------------------------------------------------
__global__ __launch_bounds__(256) void reduce_gather_kernel(
    const float* __restrict__ z, const float* __restrict__ cb,
    const u64* __restrict__ part, int* __restrict__ hist,
    float* __restrict__ lossAcc, float* __restrict__ out) {
    const int t = blockIdx.x * 256 + threadIdx.x;
    u64 best = part[t];
#pragma unroll
    for (int s = 1; s < NSLICE; ++s) {
        u64 p = part[(size_t)s * N_TOK + t];
        if (p < best) best = p;
    }
    const int idx = (int)(best & 0xFFFFFFFFull);
    out[IDX_OFF + t] = (float)idx;
    atomicAdd(&hist[idx], 1);

    const float4* ev = (const float4*)(cb + (size_t)idx * EDIM);
    const float4* zv = (const float4*)(z + (size_t)t * EDIM);
    float* o = out + ZQ_OFF + (size_t)t * EDIM;  // out+1: only 4B-aligned -> scalar stores
    float acc = 0.0f;
#pragma unroll
    for (int j = 0; j < 16; ++j) {
        float4 e = ev[j], zz = zv[j];
        float d;
        d = e.x - zz.x; o[4 * j + 0] = zz.x + d; acc = __builtin_fmaf(d, d, acc);
        d = e.y - zz.y; o[4 * j + 1] = zz.y + d; acc = __builtin_fmaf(d, d, acc);
        d = e.z - zz.z; o[4 * j + 2] = zz.z + d; acc = __builtin_fmaf(d, d, acc);
        d = e.w - zz.w; o[4 * j + 3] = zz.w + d; acc = __builtin_fmaf(d, d, acc);
    }
    __shared__ float red[256];
    red[threadIdx.x] = acc;
    __syncthreads();
    for (int s = 128; s > 0; s >>= 1) {
        if (threadIdx.x < s) red[threadIdx.x] += red[threadIdx.x + s];
        __syncthreads();
    }
    if (threadIdx.x == 0) atomicAdd(lossAcc, red[0]);
}

// ---------------------------------------------------------------------------
// Kernel D: perplexity from histogram + loss finalize. (unchanged)
// ---------------------------------------------------------------------------
__global__ __launch_bounds__(256) void finalize_kernel(
    const int* __restrict__ hist, const float* __restrict__ lossAcc,
    float* __restrict__ out) {
    __shared__ float red[256];
    float acc = 0.0f;
    for (int i = threadIdx.x; i < NE; i += 256) {
        float e = (float)hist[i] * (1.0f / 16384.0f);  // exact /n_tokens
        acc += e * logf(e + 1e-10f);
    }
    red[threadIdx.x] = acc;
    __syncthreads();
    for (int s = 128; s > 0; s >>= 1) {
        if (threadIdx.x < s) red[threadIdx.x] += red[threadIdx.x + s];
        __syncthreads();
    }
    if (threadIdx.x == 0) {
        out[PERP_OFF] = expf(-red[0]);
        float m = lossAcc[0] * (1.0f / 1048576.0f);    // exact /B*T*E
        out[0] = m + 0.25f * m;
    }
}

extern "C" void kernel_launch(void* const* d_in, const int* in_sizes, int n_in,
                              void* d_out, int out_size, void* d_ws, size_t ws_size,
                              hipStream_t stream) {
    const float* z  = (const float*)d_in[0];
    const float* cb = (const float*)d_in[1];
    float* out = (float*)d_out;

    char* ws = (char*)d_ws;
    u64*   part    = (u64*)ws;                                  // 2 MB
    float* nz      = (float*)(ws + (size_t)NSLICE * N_TOK * 8); // 64 KB
    float* ne      = nz + N_TOK;                                // 16 KB
    int*   hist    = (int*)(ne + NE);                           // 16 KB
    float* lossAcc = (float*)(hist + NE);                       // 4 B

    hipLaunchKernelGGL(norms_zero_kernel, dim3(80), dim3(256), 0, stream,
                       z, cb, nz, ne, hist, lossAcc);
    hipLaunchKernelGGL(dist_argmin_kernel,
                       dim3(N_TOK / 256, NSLICE), dim3(TPB), 0, stream,
                       z, cb, nz, ne, part);
    hipLaunchKernelGGL(reduce_gather_kernel, dim3(64), dim3(256), 0, stream,
                       z, cb, part, hist, lossAcc, out);
    hipLaunchKernelGGL(finalize_kernel, dim3(1), dim3(256), 0, stream,
                       hist, lossAcc, out);
}

// Round 4
// 255.924 us; speedup vs baseline: 6.0359x; 1.1525x over previous
//
#include <hip/hip_runtime.h>
#include <math.h>

#define N_TOK   16384
#define EDIM    64
#define NE      4096
#define NSLICE  16                       /* 16 slices x 256 codes */
#define TPB     256
#define ZQ_OFF  1
#define IDX_OFF (1 + N_TOK * EDIM)       /* 1048577 */
#define PERP_OFF (IDX_OFF + N_TOK)       /* 1064961 */

typedef unsigned long long u64;

// ---------------------------------------------------------------------------
// Kernel A: per-row squared norms replicating numpy pairwise_sum (n=64 path:
// 8 accumulators stride 8, then ((r0+r1)+(r2+r3))+((r4+r5)+(r6+r7))),
// with products ROUNDED before summation (contract off). Also zero-inits
// the histogram and loss accumulator in ws. (unchanged)
// ---------------------------------------------------------------------------
__global__ __launch_bounds__(256) void norms_zero_kernel(
    const float* __restrict__ z, const float* __restrict__ cb,
    float* __restrict__ nz, float* __restrict__ ne,
    int* __restrict__ hist, float* __restrict__ lossAcc) {
#pragma clang fp contract(off)
    int i = blockIdx.x * 256 + threadIdx.x;
    if (i < NE) hist[i] = 0;
    if (i == 0) lossAcc[0] = 0.0f;
    const float* row;
    float* dst;
    if (i < N_TOK)            { row = z  + (size_t)i * EDIM;           dst = nz + i; }
    else if (i < N_TOK + NE)  { row = cb + (size_t)(i - N_TOK) * EDIM; dst = ne + (i - N_TOK); }
    else return;

    float r[8];
#pragma unroll
    for (int j = 0; j < 8; ++j) { float v = row[j]; r[j] = v * v; }
#pragma unroll
    for (int b = 8; b < 64; b += 8) {
#pragma unroll
        for (int j = 0; j < 8; ++j) { float v = row[b + j]; r[j] = r[j] + v * v; }
    }
    dst[0] = ((r[0] + r[1]) + (r[2] + r[3])) + ((r[4] + r[5]) + (r[6] + r[7]));
}

// ---------------------------------------------------------------------------
// Kernel B (v5): 16x8 register tile, 256x128 block tile, 2 blocks/CU.
// Model: R = FMA-instr per ds_read_b128 = 4tc/(t+c) must be >=~24 to
// balance the 12cyc/b128 LDS pipe vs 4 SIMDs, AND regs must allow 2
// blocks/CU. Round-1 (8x8): R=16 -> LDS-bound (135us). Round-3 (16x16):
// R=32 but acc=256 regs -> spill + 1 wave/SIMD -> latency death (246us).
// v5 (16x8): R=21.3, LDS 61us ~= VALU 60us floor; acc=128 + cf 32 +
// bd/bk 32 -> ~215 peak regs -> fits 256 at launch_bounds(256,2).
// LDS 80KB = z-tile 64KB full-dim (staged ONCE, round-3's 0-conflict
// swizzle [q][tok^q]) + code tile 16KB per dim-phase (K-split: 4 stagings
// of 4KB global each, 128B-line coalesced) -> exactly 2 blocks/CU.
// Numerics: per-(token,code) dot is the SAME sequential q-ascending,
// x->w-ascending fp32 FMA chain (chunks split CODES, not dims -> chain
// intact, bits identical -> ties exact). d = fma(-2, dot, nz+ne[k]);
// running strict-< argmin over ascending k (chunk0 then chunk1, j asc)
// == first index; u64 pack (d_bits<<32)|k then cross-cg LDS u64 min
// (round-3's verified reduction; d>0 so float bits monotone).
// ---------------------------------------------------------------------------
__global__ __launch_bounds__(256, 2) void dist_argmin_kernel(
    const float* __restrict__ z, const float* __restrict__ cb,
    const float* __restrict__ nz, const float* __restrict__ ne,
    u64* __restrict__ part) {
    __shared__ float4 zt[16 * 256];      // 64 KB: [q][token^q], 256 tokens
    __shared__ float4 ct[8 * 128];       // 16 KB: [ql][code^ql], 128 codes, 1 phase
    const int tid   = threadIdx.x;
    const int tg    = tid & 15;          // token lane-group (16 tokens, stride 16)
    const int cg    = tid >> 4;          // code group (8 codes)
    const int tok0  = blockIdx.x * 256;
    const int kb0   = blockIdx.y * 256;  // slice base (256 codes = 2 chunks)

    // ---- stage z tile once (round-3 pattern: measured 0 bank conflicts)
    {
        const float4* zp = (const float4*)z + (size_t)tok0 * 16;
#pragma unroll
        for (int r = 0; r < 16; ++r) {
            const int f   = r * 256 + tid;   // 0..4095
            const int row = f >> 4;          // local token
            const int q   = f & 15;          // dim-group
            zt[q * 256 + (row ^ q)] = zp[f];
        }
    }

    float bd[16];
    int   bk[16];
#pragma unroll
    for (int i = 0; i < 16; ++i) { bd[i] = __builtin_inff(); bk[i] = 0; }

#pragma unroll 1
    for (int ch = 0; ch < 2; ++ch) {
        const int kb = kb0 + ch * 128;
        float acc[16][8];
#pragma unroll
        for (int i = 0; i < 16; ++i)
#pragma unroll
            for (int j = 0; j < 8; ++j) acc[i][j] = 0.0f;

#pragma unroll 1
        for (int p = 0; p < 2; ++p) {
            __syncthreads();             // previous ct readers done
            {
                // codes kb..kb+127, float4-dims 8p..8p+7; 4 float4/thread.
                // lanes cover 8-consecutive-float4 runs = full 128B lines.
                const float4* cp = (const float4*)cb;
#pragma unroll
                for (int r = 0; r < 4; ++r) {
                    const int f    = r * 256 + tid;  // 0..1023
                    const int code = f >> 3;         // local code
                    const int ql   = f & 7;          // phase-local dim-group
                    ct[ql * 128 + (code ^ ql)] =
                        cp[(size_t)(kb + code) * 16 + 8 * p + ql];
                }
            }
            __syncthreads();

#pragma unroll 2
            for (int ql = 0; ql < 8; ++ql) {
                const int q = 8 * p + ql;            // global dim-group
                float4 cf[8];
#pragma unroll
                for (int j = 0; j < 8; ++j)
                    cf[j] = ct[ql * 128 + ((cg * 8 + j) ^ ql)];
#pragma unroll
                for (int i = 0; i < 16; ++i) {
                    const float4 zf = zt[q * 256 + ((i * 16 + tg) ^ q)];
#pragma unroll
                    for (int j = 0; j < 8; ++j) {
                        acc[i][j] = __builtin_fmaf(zf.x, cf[j].x, acc[i][j]);
                        acc[i][j] = __builtin_fmaf(zf.y, cf[j].y, acc[i][j]);
                        acc[i][j] = __builtin_fmaf(zf.z, cf[j].z, acc[i][j]);
                        acc[i][j] = __builtin_fmaf(zf.w, cf[j].w, acc[i][j]);
                    }
                }
            }
        }

        // ---- per-chunk epilogue: d + running argmin (strict <, k ascending)
        float sne[8];
#pragma unroll
        for (int j = 0; j < 8; ++j) sne[j] = ne[kb + cg * 8 + j];
#pragma unroll
        for (int i = 0; i < 16; ++i) {
            const float tz = nz[tok0 + i * 16 + tg];
#pragma unroll
            for (int j = 0; j < 8; ++j) {
                const float d = __builtin_fmaf(-2.0f, acc[i][j], tz + sne[j]);
                const int   k = kb + cg * 8 + j;
                if (d < bd[i]) { bd[i] = d; bk[i] = k; }
            }
        }
    }

    // ---- cross-thread (cg) reduction: overlay on zt (done with it)
    __syncthreads();
    u64* red = (u64*)zt;                 // 16 cg x 256 tokens = 32 KB
#pragma unroll
    for (int i = 0; i < 16; ++i)
        red[cg * 256 + i * 16 + tg] =
            ((u64)__float_as_uint(bd[i]) << 32) | (u64)bk[i];
    __syncthreads();
    u64 b = red[tid];
#pragma unroll
    for (int s = 1; s < 16; ++s) {
        const u64 p = red[s * 256 + tid];
        if (p < b) b = p;
    }
    part[(size_t)blockIdx.y * N_TOK + tok0 + tid] = b;
}

// ---------------------------------------------------------------------------
// Kernel C: combine 16 slice-partials (u64 min keeps first-index tie-break),
// write idx as float, histogram, gather z_q, write z_q_st = z + (z_q - z)
// exactly as the reference computes it, and accumulate sum((z_q - z)^2).
// (unchanged)
// ---------------------------------------------------------------------------
__global__ __launch_bounds__(256) void reduce_gather_kernel(
    const float* __restrict__ z, const float* __restrict__ cb,
    const u64* __restrict__ part, int* __restrict__ hist,
    float* __restrict__ lossAcc, float* __restrict__ out) {
    const int t = blockIdx.x * 256 + threadIdx.x;
    u64 best = part[t];
#pragma unroll
    for (int s = 1; s < NSLICE; ++s) {
        u64 p = part[(size_t)s * N_TOK + t];
        if (p < best) best = p;
    }
    const int idx = (int)(best & 0xFFFFFFFFull);
    out[IDX_OFF + t] = (float)idx;
    atomicAdd(&hist[idx], 1);

    const float4* ev = (const float4*)(cb + (size_t)idx * EDIM);
    const float4* zv = (const float4*)(z + (size_t)t * EDIM);
    float* o = out + ZQ_OFF + (size_t)t * EDIM;  // out+1: only 4B-aligned -> scalar stores
    float acc = 0.0f;
#pragma unroll
    for (int j = 0; j < 16; ++j) {
        float4 e = ev[j], zz = zv[j];
        float d;
        d = e.x - zz.x; o[4 * j + 0] = zz.x + d; acc = __builtin_fmaf(d, d, acc);
        d = e.y - zz.y; o[4 * j + 1] = zz.y + d; acc = __builtin_fmaf(d, d, acc);
        d = e.z - zz.z; o[4 * j + 2] = zz.z + d; acc = __builtin_fmaf(d, d, acc);
        d = e.w - zz.w; o[4 * j + 3] = zz.w + d; acc = __builtin_fmaf(d, d, acc);
    }
    __shared__ float red[256];
    red[threadIdx.x] = acc;
    __syncthreads();
    for (int s = 128; s > 0; s >>= 1) {
        if (threadIdx.x < s) red[threadIdx.x] += red[threadIdx.x + s];
        __syncthreads();
    }
    if (threadIdx.x == 0) atomicAdd(lossAcc, red[0]);
}

// ---------------------------------------------------------------------------
// Kernel D: perplexity from histogram + loss finalize. (unchanged)
// ---------------------------------------------------------------------------
__global__ __launch_bounds__(256) void finalize_kernel(
    const int* __restrict__ hist, const float* __restrict__ lossAcc,
    float* __restrict__ out) {
    __shared__ float red[256];
    float acc = 0.0f;
    for (int i = threadIdx.x; i < NE; i += 256) {
        float e = (float)hist[i] * (1.0f / 16384.0f);  // exact /n_tokens
        acc += e * logf(e + 1e-10f);
    }
    red[threadIdx.x] = acc;
    __syncthreads();
    for (int s = 128; s > 0; s >>= 1) {
        if (threadIdx.x < s) red[threadIdx.x] += red[threadIdx.x + s];
        __syncthreads();
    }
    if (threadIdx.x == 0) {
        out[PERP_OFF] = expf(-red[0]);
        float m = lossAcc[0] * (1.0f / 1048576.0f);    // exact /B*T*E
        out[0] = m + 0.25f * m;
    }
}

extern "C" void kernel_launch(void* const* d_in, const int* in_sizes, int n_in,
                              void* d_out, int out_size, void* d_ws, size_t ws_size,
                              hipStream_t stream) {
    const float* z  = (const float*)d_in[0];
    const float* cb = (const float*)d_in[1];
    float* out = (float*)d_out;

    char* ws = (char*)d_ws;
    u64*   part    = (u64*)ws;                                  // 2 MB
    float* nz      = (float*)(ws + (size_t)NSLICE * N_TOK * 8); // 64 KB
    float* ne      = nz + N_TOK;                                // 16 KB
    int*   hist    = (int*)(ne + NE);                           // 16 KB
    float* lossAcc = (float*)(hist + NE);                       // 4 B

    hipLaunchKernelGGL(norms_zero_kernel, dim3(80), dim3(256), 0, stream,
                       z, cb, nz, ne, hist, lossAcc);
    hipLaunchKernelGGL(dist_argmin_kernel,
                       dim3(N_TOK / 256, NSLICE), dim3(TPB), 0, stream,
                       z, cb, nz, ne, part);
    hipLaunchKernelGGL(reduce_gather_kernel, dim3(64), dim3(256), 0, stream,
                       z, cb, part, hist, lossAcc, out);
    hipLaunchKernelGGL(finalize_kernel, dim3(1), dim3(256), 0, stream,
                       hist, lossAcc, out);
}

// Round 5
// 252.893 us; speedup vs baseline: 6.1082x; 1.0120x over previous
//
#include <hip/hip_runtime.h>
#include <math.h>

#define N_TOK   16384
#define EDIM    64
#define NE      4096
#define NSLICE  16                       /* 16 slices x 256 codes */
#define TPB     256
#define ZQ_OFF  1
#define IDX_OFF (1 + N_TOK * EDIM)       /* 1048577 */
#define PERP_OFF (IDX_OFF + N_TOK)       /* 1064961 */

typedef unsigned long long u64;

// ---------------------------------------------------------------------------
// Kernel A: per-row squared norms replicating numpy pairwise_sum (n=64 path:
// 8 accumulators stride 8, then ((r0+r1)+(r2+r3))+((r4+r5)+(r6+r7))),
// with products ROUNDED before summation (contract off). Also zero-inits
// the histogram and loss accumulator in ws. (unchanged)
// ---------------------------------------------------------------------------
__global__ __launch_bounds__(256) void norms_zero_kernel(
    const float* __restrict__ z, const float* __restrict__ cb,
    float* __restrict__ nz, float* __restrict__ ne,
    int* __restrict__ hist, float* __restrict__ lossAcc) {
#pragma clang fp contract(off)
    int i = blockIdx.x * 256 + threadIdx.x;
    if (i < NE) hist[i] = 0;
    if (i == 0) lossAcc[0] = 0.0f;
    const float* row;
    float* dst;
    if (i < N_TOK)            { row = z  + (size_t)i * EDIM;           dst = nz + i; }
    else if (i < N_TOK + NE)  { row = cb + (size_t)(i - N_TOK) * EDIM; dst = ne + (i - N_TOK); }
    else return;

    float r[8];
#pragma unroll
    for (int j = 0; j < 8; ++j) { float v = row[j]; r[j] = v * v; }
#pragma unroll
    for (int b = 8; b < 64; b += 8) {
#pragma unroll
        for (int j = 0; j < 8; ++j) { float v = row[b + j]; r[j] = r[j] + v * v; }
    }
    dst[0] = ((r[0] + r[1]) + (r[2] + r[3])) + ((r[4] + r[5]) + (r[6] + r[7]));
}

// ---------------------------------------------------------------------------
// Kernel B (v6): v5's 16x8 tile + amdgpu_waves_per_eu(2,2).
// Round-4 post-mortem: launch_bounds(256,2) only sets MIN waves/EU; the
// backend targeted 4 waves/EU (128 VGPRs) and spilled ~90 regs to scratch
// (WRITE_SIZE 168 MB vs 2 MB legit; FETCH 94 MB vs 6.4 MB in round-3 ->
// scratch thrash also killed L3 absorption of z re-reads). LDS (80 KB ->
// 2 blocks/CU) already caps occupancy at 2 waves/EU, so a 256-VGPR budget
// is free: pin it with waves_per_eu(2,2).
// Tile model unchanged: R = 4tc/(t+c) = 21.3 FMA per ds_read_b128 ->
// LDS pipe ~61us/CU ~= VALU floor ~60us/CU, overlapped across 8 waves/CU.
// acc 128 + cf 32 + bd/bk 32 + misc ~= 215 regs < 256 -> no spill.
// LDS 80KB = z-tile 64KB full-dim (staged ONCE, 0-conflict swizzle
// [q][tok^q]) + code tile 16KB per dim-phase (K-split: 4 stagings of 4KB
// global each, 128B-line coalesced).
// Numerics: per-(token,code) dot is the SAME sequential q-ascending,
// x->w-ascending fp32 FMA chain (chunks split CODES, not dims -> chain
// intact, bits identical -> ties exact). d = fma(-2, dot, nz+ne[k]);
// running strict-< argmin over ascending k (chunk0 then chunk1, j asc)
// == first index; u64 pack (d_bits<<32)|k then cross-cg LDS u64 min
// (d>0 so float bits monotone). Verified absmax=0 in round 4.
// ---------------------------------------------------------------------------
__global__ __launch_bounds__(256)
__attribute__((amdgpu_waves_per_eu(2, 2)))
void dist_argmin_kernel(
    const float* __restrict__ z, const float* __restrict__ cb,
    const float* __restrict__ nz, const float* __restrict__ ne,
    u64* __restrict__ part) {
    __shared__ float4 zt[16 * 256];      // 64 KB: [q][token^q], 256 tokens
    __shared__ float4 ct[8 * 128];       // 16 KB: [ql][code^ql], 128 codes, 1 phase
    const int tid   = threadIdx.x;
    const int tg    = tid & 15;          // token lane-group (16 tokens, stride 16)
    const int cg    = tid >> 4;          // code group (8 codes)
    const int tok0  = blockIdx.x * 256;
    const int kb0   = blockIdx.y * 256;  // slice base (256 codes = 2 chunks)

    // ---- stage z tile once (round-3 pattern: measured 0 bank conflicts)
    {
        const float4* zp = (const float4*)z + (size_t)tok0 * 16;
#pragma unroll
        for (int r = 0; r < 16; ++r) {
            const int f   = r * 256 + tid;   // 0..4095
            const int row = f >> 4;          // local token
            const int q   = f & 15;          // dim-group
            zt[q * 256 + (row ^ q)] = zp[f];
        }
    }

    float bd[16];
    int   bk[16];
#pragma unroll
    for (int i = 0; i < 16; ++i) { bd[i] = __builtin_inff(); bk[i] = 0; }

#pragma unroll 1
    for (int ch = 0; ch < 2; ++ch) {
        const int kb = kb0 + ch * 128;
        float acc[16][8];
#pragma unroll
        for (int i = 0; i < 16; ++i)
#pragma unroll
            for (int j = 0; j < 8; ++j) acc[i][j] = 0.0f;

#pragma unroll 1
        for (int p = 0; p < 2; ++p) {
            __syncthreads();             // previous ct readers done
            {
                // codes kb..kb+127, float4-dims 8p..8p+7; 4 float4/thread.
                // lanes cover 8-consecutive-float4 runs = full 128B lines.
                const float4* cp = (const float4*)cb;
#pragma unroll
                for (int r = 0; r < 4; ++r) {
                    const int f    = r * 256 + tid;  // 0..1023
                    const int code = f >> 3;         // local code
                    const int ql   = f & 7;          // phase-local dim-group
                    ct[ql * 128 + (code ^ ql)] =
                        cp[(size_t)(kb + code) * 16 + 8 * p + ql];
                }
            }
            __syncthreads();

#pragma unroll 2
            for (int ql = 0; ql < 8; ++ql) {
                const int q = 8 * p + ql;            // global dim-group
                float4 cf[8];
#pragma unroll
                for (int j = 0; j < 8; ++j)
                    cf[j] = ct[ql * 128 + ((cg * 8 + j) ^ ql)];
#pragma unroll
                for (int i = 0; i < 16; ++i) {
                    const float4 zf = zt[q * 256 + ((i * 16 + tg) ^ q)];
#pragma unroll
                    for (int j = 0; j < 8; ++j) {
                        acc[i][j] = __builtin_fmaf(zf.x, cf[j].x, acc[i][j]);
                        acc[i][j] = __builtin_fmaf(zf.y, cf[j].y, acc[i][j]);
                        acc[i][j] = __builtin_fmaf(zf.z, cf[j].z, acc[i][j]);
                        acc[i][j] = __builtin_fmaf(zf.w, cf[j].w, acc[i][j]);
                    }
                }
            }
        }

        // ---- per-chunk epilogue: d + running argmin (strict <, k ascending)
        float sne[8];
#pragma unroll
        for (int j = 0; j < 8; ++j) sne[j] = ne[kb + cg * 8 + j];
#pragma unroll
        for (int i = 0; i < 16; ++i) {
            const float tz = nz[tok0 + i * 16 + tg];
#pragma unroll
            for (int j = 0; j < 8; ++j) {
                const float d = __builtin_fmaf(-2.0f, acc[i][j], tz + sne[j]);
                const int   k = kb + cg * 8 + j;
                if (d < bd[i]) { bd[i] = d; bk[i] = k; }
            }
        }
    }

    // ---- cross-thread (cg) reduction: overlay on zt (done with it)
    __syncthreads();
    u64* red = (u64*)zt;                 // 16 cg x 256 tokens = 32 KB
#pragma unroll
    for (int i = 0; i < 16; ++i)
        red[cg * 256 + i * 16 + tg] =
            ((u64)__float_as_uint(bd[i]) << 32) | (u64)bk[i];
    __syncthreads();
    u64 b = red[tid];
#pragma unroll
    for (int s = 1; s < 16; ++s) {
        const u64 p = red[s * 256 + tid];
        if (p < b) b = p;
    }
    part[(size_t)blockIdx.y * N_TOK + tok0 + tid] = b;
}

// ---------------------------------------------------------------------------
// Kernel C: combine 16 slice-partials (u64 min keeps first-index tie-break),
// write idx as float, histogram, gather z_q, write z_q_st = z + (z_q - z)
// exactly as the reference computes it, and accumulate sum((z_q - z)^2).
// (unchanged)
// ---------------------------------------------------------------------------
__global__ __launch_bounds__(256) void reduce_gather_kernel(
    const float* __restrict__ z, const float* __restrict__ cb,
    const u64* __restrict__ part, int* __restrict__ hist,
    float* __restrict__ lossAcc, float* __restrict__ out) {
    const int t = blockIdx.x * 256 + threadIdx.x;
    u64 best = part[t];
#pragma unroll
    for (int s = 1; s < NSLICE; ++s) {
        u64 p = part[(size_t)s * N_TOK + t];
        if (p < best) best = p;
    }
    const int idx = (int)(best & 0xFFFFFFFFull);
    out[IDX_OFF + t] = (float)idx;
    atomicAdd(&hist[idx], 1);

    const float4* ev = (const float4*)(cb + (size_t)idx * EDIM);
    const float4* zv = (const float4*)(z + (size_t)t * EDIM);
    float* o = out + ZQ_OFF + (size_t)t * EDIM;  // out+1: only 4B-aligned -> scalar stores
    float acc = 0.0f;
#pragma unroll
    for (int j = 0; j < 16; ++j) {
        float4 e = ev[j], zz = zv[j];
        float d;
        d = e.x - zz.x; o[4 * j + 0] = zz.x + d; acc = __builtin_fmaf(d, d, acc);
        d = e.y - zz.y; o[4 * j + 1] = zz.y + d; acc = __builtin_fmaf(d, d, acc);
        d = e.z - zz.z; o[4 * j + 2] = zz.z + d; acc = __builtin_fmaf(d, d, acc);
        d = e.w - zz.w; o[4 * j + 3] = zz.w + d; acc = __builtin_fmaf(d, d, acc);
    }
    __shared__ float red[256];
    red[threadIdx.x] = acc;
    __syncthreads();
    for (int s = 128; s > 0; s >>= 1) {
        if (threadIdx.x < s) red[threadIdx.x] += red[threadIdx.x + s];
        __syncthreads();
    }
    if (threadIdx.x == 0) atomicAdd(lossAcc, red[0]);
}

// ---------------------------------------------------------------------------
// Kernel D: perplexity from histogram + loss finalize. (unchanged)
// ---------------------------------------------------------------------------
__global__ __launch_bounds__(256) void finalize_kernel(
    const int* __restrict__ hist, const float* __restrict__ lossAcc,
    float* __restrict__ out) {
    __shared__ float red[256];
    float acc = 0.0f;
    for (int i = threadIdx.x; i < NE; i += 256) {
        float e = (float)hist[i] * (1.0f / 16384.0f);  // exact /n_tokens
        acc += e * logf(e + 1e-10f);
    }
    red[threadIdx.x] = acc;
    __syncthreads();
    for (int s = 128; s > 0; s >>= 1) {
        if (threadIdx.x < s) red[threadIdx.x] += red[threadIdx.x + s];
        __syncthreads();
    }
    if (threadIdx.x == 0) {
        out[PERP_OFF] = expf(-red[0]);
        float m = lossAcc[0] * (1.0f / 1048576.0f);    // exact /B*T*E
        out[0] = m + 0.25f * m;
    }
}

extern "C" void kernel_launch(void* const* d_in, const int* in_sizes, int n_in,
                              void* d_out, int out_size, void* d_ws, size_t ws_size,
                              hipStream_t stream) {
    const float* z  = (const float*)d_in[0];
    const float* cb = (const float*)d_in[1];
    float* out = (float*)d_out;

    char* ws = (char*)d_ws;
    u64*   part    = (u64*)ws;                                  // 2 MB
    float* nz      = (float*)(ws + (size_t)NSLICE * N_TOK * 8); // 64 KB
    float* ne      = nz + N_TOK;                                // 16 KB
    int*   hist    = (int*)(ne + NE);                           // 16 KB
    float* lossAcc = (float*)(hist + NE);                       // 4 B

    hipLaunchKernelGGL(norms_zero_kernel, dim3(80), dim3(256), 0, stream,
                       z, cb, nz, ne, hist, lossAcc);
    hipLaunchKernelGGL(dist_argmin_kernel,
                       dim3(N_TOK / 256, NSLICE), dim3(TPB), 0, stream,
                       z, cb, nz, ne, part);
    hipLaunchKernelGGL(reduce_gather_kernel, dim3(64), dim3(256), 0, stream,
                       z, cb, part, hist, lossAcc, out);
    hipLaunchKernelGGL(finalize_kernel, dim3(1), dim3(256), 0, stream,
                       hist, lossAcc, out);
}

// Round 6
// 239.574 us; speedup vs baseline: 6.4478x; 1.0556x over previous
//
#include <hip/hip_runtime.h>
#include <math.h>

#define N_TOK   16384
#define EDIM    64
#define NE      4096
#define NSLICE  16                       /* 16 slices x 256 codes */
#define TPB     256
#define ZQ_OFF  1
#define IDX_OFF (1 + N_TOK * EDIM)       /* 1048577 */
#define PERP_OFF (IDX_OFF + N_TOK)       /* 1064961 */

typedef unsigned long long u64;

// ---------------------------------------------------------------------------
// Kernel A: per-row squared norms replicating numpy pairwise_sum (n=64 path:
// 8 accumulators stride 8, then ((r0+r1)+(r2+r3))+((r4+r5)+(r6+r7))),
// with products ROUNDED before summation (contract off). Also zero-inits
// the histogram and loss accumulator in ws. (unchanged)
// ---------------------------------------------------------------------------
__global__ __launch_bounds__(256) void norms_zero_kernel(
    const float* __restrict__ z, const float* __restrict__ cb,
    float* __restrict__ nz, float* __restrict__ ne,
    int* __restrict__ hist, float* __restrict__ lossAcc) {
#pragma clang fp contract(off)
    int i = blockIdx.x * 256 + threadIdx.x;
    if (i < NE) hist[i] = 0;
    if (i == 0) lossAcc[0] = 0.0f;
    const float* row;
    float* dst;
    if (i < N_TOK)            { row = z  + (size_t)i * EDIM;           dst = nz + i; }
    else if (i < N_TOK + NE)  { row = cb + (size_t)(i - N_TOK) * EDIM; dst = ne + (i - N_TOK); }
    else return;

    float r[8];
#pragma unroll
    for (int j = 0; j < 8; ++j) { float v = row[j]; r[j] = v * v; }
#pragma unroll
    for (int b = 8; b < 64; b += 8) {
#pragma unroll
        for (int j = 0; j < 8; ++j) { float v = row[b + j]; r[j] = r[j] + v * v; }
    }
    dst[0] = ((r[0] + r[1]) + (r[2] + r[3])) + ((r[4] + r[5]) + (r[6] + r[7]));
}

// ---------------------------------------------------------------------------
// Kernel B (v7): v5's 16x8 tile with __launch_bounds__(256, 1).
// Regalloc evidence across rounds: min-waves=2 (r4) and waves_per_eu(2,2)
// (r5, bit-identical counters -> attribute was a no-op) both yield
// VGPR_Count=128 with ~90 regs spilled to scratch (WRITE_SIZE 168 MB vs
// 2 MB legit). Round-3 with min-waves=1 allocated 244 VGPRs and ZERO
// spill (WRITE exactly 2 MB). So: min=1 -> clean large allocation.
// Live set here ~206 (acc 128 + cf 32 + pb 32 + addr) < 256, so expected
// allocation keeps 2 waves/SIMD; LDS 80 KB keeps 2 blocks/CU.
// Tile model: R = 4tc/(t+c) = 21.3 FMA per ds_read_b128 -> LDS pipe
// ~61us/CU ~= VALU floor ~55us/CU, overlapped across 8 waves/CU.
// LDS 80KB = z-tile 64KB full-dim (staged ONCE, 0-conflict swizzle
// [q][tok^q]) + code tile 16KB per dim-phase (K-split: 4 stagings of 4KB
// global each, 128B-line coalesced).
// Numerics: per-(token,code) dot is the SAME sequential q-ascending,
// x->w-ascending fp32 FMA chain (chunks split CODES, not dims -> chain
// intact, bits identical -> ties exact). d = fma(-2, dot, nz+ne[k]);
// running strict-< argmin over ascending k (chunk0 then chunk1, j asc)
// == first index; u64 pack (d_bits<<32)|k then cross-cg LDS u64 min
// (d>0 so float bits monotone). Verified absmax=0 in rounds 4/5.
// ---------------------------------------------------------------------------
__global__ __launch_bounds__(256, 1)
void dist_argmin_kernel(
    const float* __restrict__ z, const float* __restrict__ cb,
    const float* __restrict__ nz, const float* __restrict__ ne,
    u64* __restrict__ part) {
    __shared__ float4 zt[16 * 256];      // 64 KB: [q][token^q], 256 tokens
    __shared__ float4 ct[8 * 128];       // 16 KB: [ql][code^ql], 128 codes, 1 phase
    const int tid   = threadIdx.x;
    const int tg    = tid & 15;          // token lane-group (16 tokens, stride 16)
    const int cg    = tid >> 4;          // code group (8 codes)
    const int tok0  = blockIdx.x * 256;
    const int kb0   = blockIdx.y * 256;  // slice base (256 codes = 2 chunks)

    // ---- stage z tile once (round-3 pattern: measured 0 bank conflicts)
    {
        const float4* zp = (const float4*)z + (size_t)tok0 * 16;
#pragma unroll
        for (int r = 0; r < 16; ++r) {
            const int f   = r * 256 + tid;   // 0..4095
            const int row = f >> 4;          // local token
            const int q   = f & 15;          // dim-group
            zt[q * 256 + (row ^ q)] = zp[f];
        }
    }

    float bd[16];
    int   bk[16];
#pragma unroll
    for (int i = 0; i < 16; ++i) { bd[i] = __builtin_inff(); bk[i] = 0; }

#pragma unroll 1
    for (int ch = 0; ch < 2; ++ch) {
        const int kb = kb0 + ch * 128;
        float acc[16][8];
#pragma unroll
        for (int i = 0; i < 16; ++i)
#pragma unroll
            for (int j = 0; j < 8; ++j) acc[i][j] = 0.0f;

#pragma unroll 1
        for (int p = 0; p < 2; ++p) {
            __syncthreads();             // previous ct readers done
            {
                // codes kb..kb+127, float4-dims 8p..8p+7; 4 float4/thread.
                // lanes cover 8-consecutive-float4 runs = full 128B lines.
                const float4* cp = (const float4*)cb;
#pragma unroll
                for (int r = 0; r < 4; ++r) {
                    const int f    = r * 256 + tid;  // 0..1023
                    const int code = f >> 3;         // local code
                    const int ql   = f & 7;          // phase-local dim-group
                    ct[ql * 128 + (code ^ ql)] =
                        cp[(size_t)(kb + code) * 16 + 8 * p + ql];
                }
            }
            __syncthreads();

#pragma unroll 2
            for (int ql = 0; ql < 8; ++ql) {
                const int q = 8 * p + ql;            // global dim-group
                float4 cf[8];
#pragma unroll
                for (int j = 0; j < 8; ++j)
                    cf[j] = ct[ql * 128 + ((cg * 8 + j) ^ ql)];
#pragma unroll
                for (int i = 0; i < 16; ++i) {
                    const float4 zf = zt[q * 256 + ((i * 16 + tg) ^ q)];
#pragma unroll
                    for (int j = 0; j < 8; ++j) {
                        acc[i][j] = __builtin_fmaf(zf.x, cf[j].x, acc[i][j]);
                        acc[i][j] = __builtin_fmaf(zf.y, cf[j].y, acc[i][j]);
                        acc[i][j] = __builtin_fmaf(zf.z, cf[j].z, acc[i][j]);
                        acc[i][j] = __builtin_fmaf(zf.w, cf[j].w, acc[i][j]);
                    }
                }
            }
        }

        // ---- per-chunk epilogue: d + running argmin (strict <, k ascending)
        float sne[8];
#pragma unroll
        for (int j = 0; j < 8; ++j) sne[j] = ne[kb + cg * 8 + j];
#pragma unroll
        for (int i = 0; i < 16; ++i) {
            const float tz = nz[tok0 + i * 16 + tg];
#pragma unroll
            for (int j = 0; j < 8; ++j) {
                const float d = __builtin_fmaf(-2.0f, acc[i][j], tz + sne[j]);
                const int   k = kb + cg * 8 + j;
                if (d < bd[i]) { bd[i] = d; bk[i] = k; }
            }
        }
    }

    // ---- cross-thread (cg) reduction: overlay on zt (done with it)
    __syncthreads();
    u64* red = (u64*)zt;                 // 16 cg x 256 tokens = 32 KB
#pragma unroll
    for (int i = 0; i < 16; ++i)
        red[cg * 256 + i * 16 + tg] =
            ((u64)__float_as_uint(bd[i]) << 32) | (u64)bk[i];
    __syncthreads();
    u64 b = red[tid];
#pragma unroll
    for (int s = 1; s < 16; ++s) {
        const u64 p = red[s * 256 + tid];
        if (p < b) b = p;
    }
    part[(size_t)blockIdx.y * N_TOK + tok0 + tid] = b;
}

// ---------------------------------------------------------------------------
// Kernel C: combine 16 slice-partials (u64 min keeps first-index tie-break),
// write idx as float, histogram, gather z_q, write z_q_st = z + (z_q - z)
// exactly as the reference computes it, and accumulate sum((z_q - z)^2).
// (unchanged)
// ---------------------------------------------------------------------------
__global__ __launch_bounds__(256) void reduce_gather_kernel(
    const float* __restrict__ z, const float* __restrict__ cb,
    const u64* __restrict__ part, int* __restrict__ hist,
    float* __restrict__ lossAcc, float* __restrict__ out) {
    const int t = blockIdx.x * 256 + threadIdx.x;
    u64 best = part[t];
#pragma unroll
    for (int s = 1; s < NSLICE; ++s) {
        u64 p = part[(size_t)s * N_TOK + t];
        if (p < best) best = p;
    }
    const int idx = (int)(best & 0xFFFFFFFFull);
    out[IDX_OFF + t] = (float)idx;
    atomicAdd(&hist[idx], 1);

    const float4* ev = (const float4*)(cb + (size_t)idx * EDIM);
    const float4* zv = (const float4*)(z + (size_t)t * EDIM);
    float* o = out + ZQ_OFF + (size_t)t * EDIM;  // out+1: only 4B-aligned -> scalar stores
    float acc = 0.0f;
#pragma unroll
    for (int j = 0; j < 16; ++j) {
        float4 e = ev[j], zz = zv[j];
        float d;
        d = e.x - zz.x; o[4 * j + 0] = zz.x + d; acc = __builtin_fmaf(d, d, acc);
        d = e.y - zz.y; o[4 * j + 1] = zz.y + d; acc = __builtin_fmaf(d, d, acc);
        d = e.z - zz.z; o[4 * j + 2] = zz.z + d; acc = __builtin_fmaf(d, d, acc);
        d = e.w - zz.w; o[4 * j + 3] = zz.w + d; acc = __builtin_fmaf(d, d, acc);
    }
    __shared__ float red[256];
    red[threadIdx.x] = acc;
    __syncthreads();
    for (int s = 128; s > 0; s >>= 1) {
        if (threadIdx.x < s) red[threadIdx.x] += red[threadIdx.x + s];
        __syncthreads();
    }
    if (threadIdx.x == 0) atomicAdd(lossAcc, red[0]);
}

// ---------------------------------------------------------------------------
// Kernel D: perplexity from histogram + loss finalize. (unchanged)
// ---------------------------------------------------------------------------
__global__ __launch_bounds__(256) void finalize_kernel(
    const int* __restrict__ hist, const float* __restrict__ lossAcc,
    float* __restrict__ out) {
    __shared__ float red[256];
    float acc = 0.0f;
    for (int i = threadIdx.x; i < NE; i += 256) {
        float e = (float)hist[i] * (1.0f / 16384.0f);  // exact /n_tokens
        acc += e * logf(e + 1e-10f);
    }
    red[threadIdx.x] = acc;
    __syncthreads();
    for (int s = 128; s > 0; s >>= 1) {
        if (threadIdx.x < s) red[threadIdx.x] += red[threadIdx.x + s];
        __syncthreads();
    }
    if (threadIdx.x == 0) {
        out[PERP_OFF] = expf(-red[0]);
        float m = lossAcc[0] * (1.0f / 1048576.0f);    // exact /B*T*E
        out[0] = m + 0.25f * m;
    }
}

extern "C" void kernel_launch(void* const* d_in, const int* in_sizes, int n_in,
                              void* d_out, int out_size, void* d_ws, size_t ws_size,
                              hipStream_t stream) {
    const float* z  = (const float*)d_in[0];
    const float* cb = (const float*)d_in[1];
    float* out = (float*)d_out;

    char* ws = (char*)d_ws;
    u64*   part    = (u64*)ws;                                  // 2 MB
    float* nz      = (float*)(ws + (size_t)NSLICE * N_TOK * 8); // 64 KB
    float* ne      = nz + N_TOK;                                // 16 KB
    int*   hist    = (int*)(ne + NE);                           // 16 KB
    float* lossAcc = (float*)(hist + NE);                       // 4 B

    hipLaunchKernelGGL(norms_zero_kernel, dim3(80), dim3(256), 0, stream,
                       z, cb, nz, ne, hist, lossAcc);
    hipLaunchKernelGGL(dist_argmin_kernel,
                       dim3(N_TOK / 256, NSLICE), dim3(TPB), 0, stream,
                       z, cb, nz, ne, part);
    hipLaunchKernelGGL(reduce_gather_kernel, dim3(64), dim3(256), 0, stream,
                       z, cb, part, hist, lossAcc, out);
    hipLaunchKernelGGL(finalize_kernel, dim3(1), dim3(256), 0, stream,
                       hist, lossAcc, out);
}